// Round 19
// baseline (622.401 us; speedup 1.0000x reference)
//
#include <hip/hip_runtime.h>

#define TPB   256
#define NXCD  8
#define FPSCALE 16777216.0f            // 2^24
#define FPINV   5.9604644775390625e-8f // 2^-24

__device__ __forceinline__ int xcc_id() {
    int x;
    asm volatile("s_getreg_b32 %0, hwreg(HW_REG_XCC_ID)" : "=s"(x));
    return x & 0xf;
}

// One-pass scatter: fixed-point int atomics into this XCD's private copy.
// Workgroup scope => no sc1 bypass => RMW executes in the local L2 (int RMW
// is a native TCC op, unlike fp32 which is microcoded/forwarded).
__global__ void scatter_int_kernel(const int* __restrict__ dst,
                                   const float* __restrict__ ea,
                                   int* __restrict__ acc,
                                   int n_edges4, int n_vert) {
    int* my = acc + (size_t)xcc_id() * n_vert;
    int i = blockIdx.x * blockDim.x + threadIdx.x;
    const int stride = gridDim.x * blockDim.x;
    for (; i < n_edges4; i += stride) {
        int4   d = reinterpret_cast<const int4*>(dst)[i];
        float4 v = reinterpret_cast<const float4*>(ea)[i];
        __hip_atomic_fetch_add(&my[d.x], __float2int_rn(v.x * FPSCALE),
                               __ATOMIC_RELAXED, __HIP_MEMORY_SCOPE_WORKGROUP);
        __hip_atomic_fetch_add(&my[d.y], __float2int_rn(v.y * FPSCALE),
                               __ATOMIC_RELAXED, __HIP_MEMORY_SCOPE_WORKGROUP);
        __hip_atomic_fetch_add(&my[d.z], __float2int_rn(v.z * FPSCALE),
                               __ATOMIC_RELAXED, __HIP_MEMORY_SCOPE_WORKGROUP);
        __hip_atomic_fetch_add(&my[d.w], __float2int_rn(v.w * FPSCALE),
                               __ATOMIC_RELAXED, __HIP_MEMORY_SCOPE_WORKGROUP);
    }
}

// Sum the NXCD int copies, convert to float, fused vertex update.
// 4 vertices/thread, int4/float4 I/O throughout.
__global__ void reduce_update_kernel(const float* __restrict__ va,
                                     const int* __restrict__ acc,
                                     const float* __restrict__ g,
                                     float* __restrict__ out, int n_vert) {
    const int gt = blockIdx.x * blockDim.x + threadIdx.x;
    const float w = g[0];
    const int v0 = gt * 4;
    if (v0 + 4 <= n_vert) {
        int4 s = reinterpret_cast<const int4*>(acc)[gt];
        #pragma unroll
        for (int k = 1; k < NXCD; ++k) {
            int4 a = reinterpret_cast<const int4*>(acc + (size_t)k * n_vert)[gt];
            s.x += a.x; s.y += a.y; s.z += a.z; s.w += a.w;
        }
        float4 c;
        c.x = (float)s.x * FPINV; c.y = (float)s.y * FPINV;
        c.z = (float)s.z * FPINV; c.w = (float)s.w * FPINV;
        float4 f0 = reinterpret_cast<const float4*>(va)[gt * 3 + 0];
        float4 f1 = reinterpret_cast<const float4*>(va)[gt * 3 + 1];
        float4 f2 = reinterpret_cast<const float4*>(va)[gt * 3 + 2];
        // rows: (f0.x f0.y f0.z)(f0.w f1.x f1.y)(f1.z f1.w f2.x)(f2.y f2.z f2.w)
        float4 o0, o1, o2;
        o0.x = f0.x; o0.y = f0.y; o0.z = f0.z + w * (f0.y - c.x) / f0.x;
        o0.w = f0.w; o1.x = f1.x; o1.y = f1.y + w * (f1.x - c.y) / f0.w;
        o1.z = f1.z; o1.w = f1.w; o2.x = f2.x + w * (f1.w - c.z) / f1.z;
        o2.y = f2.y; o2.z = f2.z; o2.w = f2.w + w * (f2.z - c.w) / f2.y;
        reinterpret_cast<float4*>(out)[gt * 3 + 0] = o0;
        reinterpret_cast<float4*>(out)[gt * 3 + 1] = o1;
        reinterpret_cast<float4*>(out)[gt * 3 + 2] = o2;
    } else {
        for (int i = v0; i < n_vert; ++i) {
            int s = 0;
            for (int k = 0; k < NXCD; ++k) s += acc[(size_t)k * n_vert + i];
            float c = (float)s * FPINV;
            float A = va[3 * i], b = va[3 * i + 1], x = va[3 * i + 2];
            out[3 * i]     = A;
            out[3 * i + 1] = b;
            out[3 * i + 2] = x + w * (b - c) / A;
        }
    }
}

// ---- fallback (insufficient scratch): device-scope fp atomics ----
__global__ void scatter_add_dev_kernel(const int* __restrict__ dst,
                                       const float* __restrict__ ea,
                                       float* __restrict__ acc, int n_edges4) {
    int i = blockIdx.x * blockDim.x + threadIdx.x;
    const int stride = gridDim.x * blockDim.x;
    for (; i < n_edges4; i += stride) {
        int4   d = reinterpret_cast<const int4*>(dst)[i];
        float4 v = reinterpret_cast<const float4*>(ea)[i];
        atomicAdd(&acc[d.x], v.x);
        atomicAdd(&acc[d.y], v.y);
        atomicAdd(&acc[d.z], v.z);
        atomicAdd(&acc[d.w], v.w);
    }
}

__global__ void update_kernel(const float* __restrict__ va,
                              const float* __restrict__ cbar,
                              const float* __restrict__ g,
                              float* __restrict__ out, int n) {
    int i = blockIdx.x * blockDim.x + threadIdx.x;
    if (i >= n) return;
    float A = va[3 * i], b = va[3 * i + 1], x = va[3 * i + 2];
    out[3 * i]     = A;
    out[3 * i + 1] = b;
    out[3 * i + 2] = x + g[0] * (b - cbar[i]) / A;
}

extern "C" void kernel_launch(void* const* d_in, const int* in_sizes, int n_in,
                              void* d_out, int out_size, void* d_ws, size_t ws_size,
                              hipStream_t stream) {
    const float* vertex_attr = (const float*)d_in[0];
    const int*   edgeij      = (const int*)d_in[1];   // row 0 = dst
    const float* edge_attr   = (const float*)d_in[2];
    const float* g           = (const float*)d_in[3];

    const int n_vert = in_sizes[0] / 3;
    const int n_edge = in_sizes[2];
    const int n_edges4 = n_edge / 4;

    const size_t need = (size_t)NXCD * n_vert * sizeof(int);

    if (ws_size >= need) {
        int* acc = (int*)d_ws;
        hipMemsetAsync(acc, 0, need, stream);   // 32 MB, ~5 us

        scatter_int_kernel<<<4096, TPB, 0, stream>>>(edgeij, edge_attr, acc,
                                                     n_edges4, n_vert);

        const int uthreads = (n_vert + 3) / 4;
        reduce_update_kernel<<<(uthreads + TPB - 1) / TPB, TPB, 0, stream>>>(
            vertex_attr, acc, g, (float*)d_out, n_vert);
    } else {
        float* cbar = (float*)d_ws;
        hipMemsetAsync(cbar, 0, (size_t)n_vert * sizeof(float), stream);
        scatter_add_dev_kernel<<<4096, TPB, 0, stream>>>(edgeij, edge_attr, cbar,
                                                         n_edges4);
        update_kernel<<<(n_vert + TPB - 1) / TPB, TPB, 0, stream>>>(
            vertex_attr, cbar, g, (float*)d_out, n_vert);
    }
}

// Round 20
// 111.631 us; speedup vs baseline: 5.5755x; 5.5755x over previous
//
#include <hip/hip_runtime.h>

#define TPB    256
#define VSHIFT 14
#define VBUCK  (1 << VSHIFT)        // 16384 vertices per bucket
#define NBMAX  256                  // array sizing; actual nb = 62
#define EPT    16                   // edges/thread/round
#define ROUND  (TPB * EPT)          // 4096 edges/round
#define RPB    4                    // rounds per block
#define PBLK   (ROUND * RPB)        // 16384 edges/block
#define SPLITMAX 8                  // accumulate sub-blocks per bucket
#define ATPB   1024                 // accumulate threads per block
#define KDEP   8                    // 16B loads in flight per thread

#define FPSCALE     16777216.0f            // 2^24
#define FPINV       5.9604644775390625e-8f // 2^-24

typedef unsigned uint32x4 __attribute__((ext_vector_type(4)));

__device__ __forceinline__ unsigned long long pack_pair(int d, float v) {
    return (unsigned long long)(unsigned)d |
           ((unsigned long long)__float_as_uint(v) << 32);
}

// Raw 16B global load, NOT waited — caller must s_waitcnt vmcnt(0) before use.
__device__ __forceinline__ uint32x4 gload16_async(const void* p) {
    uint32x4 r;
    asm volatile("global_load_dwordx4 %0, %1, off"
                 : "=&v"(r) : "v"(p));
    return r;
}

// Exclusive scan across TPB threads; also returns block total (uniform).
__device__ __forceinline__ int block_excl_scan(int v, int t, int* wsum, int* total) {
    int s = v;
    #pragma unroll
    for (int d = 1; d < 64; d <<= 1) {
        int u = __shfl_up(s, d);
        if ((t & 63) >= d) s += u;
    }
    if ((t & 63) == 63) wsum[t >> 6] = s;
    __syncthreads();
    int add = 0;
    #pragma unroll
    for (int w = 0; w < TPB / 64; ++w)
        if (w < (t >> 6)) add += wsum[w];
    int tot = wsum[0] + wsum[1] + wsum[2] + wsum[3];
    __syncthreads();                 // wsum safe for reuse
    *total = tot;
    return s + add - v;
}

// Per-ROUND bucket histograms histp_t[blk][round][t] + per-block totals
// histp_b[t][blk] for the row scan.
__global__ void hist_rounds_kernel(const int* __restrict__ dst, long long n_edge,
                                   int nblk, int* __restrict__ histp_t,
                                   int* __restrict__ histp_b) {
    __shared__ int h[NBMAX];
    const int t = threadIdx.x;
    const long long bbase = (long long)blockIdx.x * PBLK;
    int total = 0;
    for (int r = 0; r < RPB; ++r) {
        h[t] = 0;
        __syncthreads();
        const long long rbase = bbase + (long long)r * ROUND;
        #pragma unroll
        for (int j = 0; j < EPT / 4; ++j) {
            long long e = rbase + ((long long)j * TPB + t) * 4;
            if (e + 4 <= n_edge) {
                int4 d = *reinterpret_cast<const int4*>(dst + e);
                atomicAdd(&h[d.x >> VSHIFT], 1);
                atomicAdd(&h[d.y >> VSHIFT], 1);
                atomicAdd(&h[d.z >> VSHIFT], 1);
                atomicAdd(&h[d.w >> VSHIFT], 1);
            } else {
                for (int q = 0; q < 4; ++q) {
                    long long ee = e + q;
                    if (ee < n_edge) atomicAdd(&h[dst[ee] >> VSHIFT], 1);
                }
            }
        }
        __syncthreads();
        int hv = h[t];
        histp_t[((size_t)blockIdx.x * RPB + r) * NBMAX + t] = hv;
        total += hv;
        // safe: each thread touches only its own h[t] next round
    }
    histp_b[(size_t)t * nblk + blockIdx.x] = total;
}

// One block per bucket: exclusive-scan its row of per-block counts in place;
// write the bucket total.
__global__ void row_scan_kernel(int* __restrict__ histp, int nblk,
                                int* __restrict__ totals) {
    __shared__ int wsum[TPB / 64];
    const int t = threadIdx.x;
    int* row = histp + (size_t)blockIdx.x * nblk;
    int carry = 0;
    for (int base = 0; base < nblk; base += TPB) {
        int v = (base + t < nblk) ? row[base + t] : 0;
        int tot;
        int excl = block_excl_scan(v, t, wsum, &tot);
        if (base + t < nblk) row[base + t] = carry + excl;
        carry += tot;
        __syncthreads();
    }
    if (t == 0) totals[blockIdx.x] = carry;
}

// Exclusive scan of bucket totals -> bucket base offsets (base[NBMAX+1]).
__global__ void base_scan_kernel(const int* __restrict__ totals, int nb,
                                 int* __restrict__ base) {
    __shared__ int wsum[TPB / 64];
    const int t = threadIdx.x;
    int v = (t < nb) ? totals[t] : 0;
    int tot;
    int excl = block_excl_scan(v, t, wsum, &tot);
    base[t] = excl;
    if (t == TPB - 1) base[TPB] = excl + v;
}

// Partition: per round read precomputed h[t], wave-scan, scatter into sorted
// LDS stage, flush coalesced. nb=62 buckets -> avg run 66 pairs (528 B):
// wave stores are mostly single contiguous bursts.
__global__ __launch_bounds__(TPB, 4)
void partition_kernel(const int* __restrict__ dst,
                      const float* __restrict__ ea,
                      long long n_edge, int nblk,
                      const int* __restrict__ histp_t,
                      const int* __restrict__ histp_b,
                      const int* __restrict__ base,
                      unsigned long long* __restrict__ pairs) {
    __shared__ unsigned long long stage[ROUND];   // 32 KB, bucket-sorted pairs
    __shared__ int pos[NBMAX];    // round scatter cursors
    __shared__ int adj[NBMAX];    // gbase - pfx per bucket
    __shared__ int wsum[TPB / 64];

    const int t = threadIdx.x;
    const long long bbase = (long long)blockIdx.x * PBLK;
    int my_gbase = base[t] + histp_b[(size_t)t * nblk + blockIdx.x];

    int hv[RPB];
    #pragma unroll
    for (int r = 0; r < RPB; ++r)
        hv[r] = histp_t[((size_t)blockIdx.x * RPB + r) * NBMAX + t];

    if (bbase + PBLK <= n_edge) {
        // ---------- fast path: full block, prefetch double-buffer ----------
        int4   dr[2][EPT / 4];
        float4 vr[2][EPT / 4];
        #pragma unroll
        for (int j = 0; j < EPT / 4; ++j) {
            long long e = bbase + ((long long)j * TPB + t) * 4;
            dr[0][j] = *reinterpret_cast<const int4*>(dst + e);
            vr[0][j] = *reinterpret_cast<const float4*>(ea + e);
        }
        #pragma unroll
        for (int r = 0; r < RPB; ++r) {
            const int cur = r & 1, nxt = cur ^ 1;
            if (r + 1 < RPB) {                    // issue next round's loads NOW
                const long long pb = bbase + (long long)(r + 1) * ROUND;
                #pragma unroll
                for (int j = 0; j < EPT / 4; ++j) {
                    long long e = pb + ((long long)j * TPB + t) * 4;
                    dr[nxt][j] = *reinterpret_cast<const int4*>(dst + e);
                    vr[nxt][j] = *reinterpret_cast<const float4*>(ea + e);
                }
            }
            int rt;
            int excl = block_excl_scan(hv[r], t, wsum, &rt);   // 2 syncs
            pos[t] = excl;
            adj[t] = my_gbase - excl;
            __syncthreads();
            #pragma unroll
            for (int j = 0; j < EPT / 4; ++j) {
                int   dd[4] = {dr[cur][j].x, dr[cur][j].y, dr[cur][j].z, dr[cur][j].w};
                float vv[4] = {vr[cur][j].x, vr[cur][j].y, vr[cur][j].z, vr[cur][j].w};
                #pragma unroll
                for (int q = 0; q < 4; ++q) {
                    int b = dd[q] >> VSHIFT;
                    int slot = atomicAdd(&pos[b], 1);
                    stage[slot] = pack_pair(dd[q], vv[q]);
                }
            }
            __syncthreads();
            #pragma unroll
            for (int i0 = 0; i0 < ROUND; i0 += TPB) {   // rt == ROUND here
                int i = i0 + t;
                unsigned long long p = stage[i];
                int b = (int)((unsigned)(p & 0xffffffffull) >> VSHIFT);
                pairs[(size_t)(adj[b] + i)] = p;
            }
            my_gbase += hv[r];
        }
    } else {
        // ---------- guarded tail path (last block only) ----------
        const long long bend = n_edge;
        for (int r = 0; r < RPB; ++r) {
            const long long rbase = bbase + (long long)r * ROUND;
            if (rbase >= bend) break;              // uniform across block

            int4   dreg[EPT / 4];
            float4 vreg[EPT / 4];
            int    nval[EPT / 4];
            #pragma unroll
            for (int j = 0; j < EPT / 4; ++j) {
                long long e = rbase + ((long long)j * TPB + t) * 4;
                if (e + 4 <= bend) {
                    dreg[j] = *reinterpret_cast<const int4*>(dst + e);
                    vreg[j] = *reinterpret_cast<const float4*>(ea + e);
                    nval[j] = 4;
                } else {
                    int dd[4] = {0, 0, 0, 0};
                    float vv[4] = {0.f, 0.f, 0.f, 0.f};
                    int nv = 0;
                    for (int q = 0; q < 4; ++q) {
                        long long ee = e + q;
                        if (ee < bend) { dd[q] = dst[ee]; vv[q] = ea[ee]; nv = q + 1; }
                    }
                    dreg[j] = make_int4(dd[0], dd[1], dd[2], dd[3]);
                    vreg[j] = make_float4(vv[0], vv[1], vv[2], vv[3]);
                    nval[j] = nv;
                }
            }

            int rt;
            int excl = block_excl_scan(hv[r], t, wsum, &rt);
            pos[t] = excl;
            adj[t] = my_gbase - excl;
            __syncthreads();

            #pragma unroll
            for (int j = 0; j < EPT / 4; ++j) {
                int   dd[4] = {dreg[j].x, dreg[j].y, dreg[j].z, dreg[j].w};
                float vv[4] = {vreg[j].x, vreg[j].y, vreg[j].z, vreg[j].w};
                #pragma unroll
                for (int q = 0; q < 4; ++q) {
                    if (q < nval[j]) {
                        int b = dd[q] >> VSHIFT;
                        int slot = atomicAdd(&pos[b], 1);
                        stage[slot] = pack_pair(dd[q], vv[q]);
                    }
                }
            }
            __syncthreads();

            for (int i = t; i < rt; i += TPB) {
                unsigned long long p = stage[i];
                int b = (int)((unsigned)(p & 0xffffffffull) >> VSHIFT);
                pairs[(size_t)(adj[b] + i)] = p;
            }
            __syncthreads();
            my_gbase += hv[r];
        }
    }
}

// split blocks per bucket: int fixed-point LDS accumulate (fast ds_add_u32),
// KDEP-deep asm-batched loads. 64 KB LDS acc (VBUCK=16384).
__global__ __launch_bounds__(ATPB)
void accum_partial_kernel(const unsigned long long* pairs,
                          const int* __restrict__ base,
                          float* __restrict__ partials, int n_vert, int nb,
                          int split) {
    __shared__ __align__(16) int acc[VBUCK];
    const int b  = blockIdx.x % nb;
    const int sp = blockIdx.x / nb;
    const int t  = threadIdx.x;
    for (int i = t; i < VBUCK; i += ATPB) acc[i] = 0;
    __syncthreads();

    const int s = base[b];
    const int e = base[b + 1];
    const long long len = e - s;
    const int i0 = s + (int)((len * sp) / split);
    const int i1 = s + (int)((len * (sp + 1)) / split);
    const int a0 = (i0 + 1) & ~1;          // first even index >= i0
    const int a1 = i1 & ~1;                // last even boundary <= i1

    if (t == 0 && (i0 & 1) && i0 < i1) {
        unsigned long long p = pairs[i0];
        atomicAdd(&acc[(int)(p & (VBUCK - 1))],
                  __float2int_rn(__uint_as_float((unsigned)(p >> 32)) * FPSCALE));
    }
    if (t == 1 && (i1 & 1) && (i1 - 1) >= i0) {
        unsigned long long p = pairs[i1 - 1];
        atomicAdd(&acc[(int)(p & (VBUCK - 1))],
                  __float2int_rn(__uint_as_float((unsigned)(p >> 32)) * FPSCALE));
    }

    const int n2 = (a1 - a0) >> 1;         // 16B (2-pair) elements
    if (n2 > 0) {
        const char* pv = reinterpret_cast<const char*>(pairs + a0);
        const int nm1 = n2 - 1;
        for (int bb = 0; bb < n2; bb += KDEP * ATPB) {
            uint32x4 q[KDEP];
            int idx[KDEP];
            #pragma unroll
            for (int k = 0; k < KDEP; ++k) {
                idx[k] = bb + t + k * ATPB;
                int ci = idx[k] < nm1 ? idx[k] : nm1;
                q[k] = gload16_async(pv + (size_t)ci * 16);
            }
            asm volatile("s_waitcnt vmcnt(0)" ::: "memory");
            __builtin_amdgcn_sched_barrier(0);
            #pragma unroll
            for (int k = 0; k < KDEP; ++k) {
                if (idx[k] < n2) {
                    atomicAdd(&acc[(int)(q[k][0] & (VBUCK - 1))],
                              __float2int_rn(__uint_as_float(q[k][1]) * FPSCALE));
                    atomicAdd(&acc[(int)(q[k][2] & (VBUCK - 1))],
                              __float2int_rn(__uint_as_float(q[k][3]) * FPSCALE));
                }
            }
        }
    }
    __syncthreads();

    float* pp = partials + (size_t)sp * n_vert;
    const int vbase = b << VSHIFT;
    for (int v4 = t * 4; v4 < VBUCK; v4 += ATPB * 4) {
        int vi = vbase + v4;
        if (vi + 4 <= n_vert) {
            int4 a = *reinterpret_cast<const int4*>(&acc[v4]);
            float4 f;
            f.x = (float)a.x * FPINV; f.y = (float)a.y * FPINV;
            f.z = (float)a.z * FPINV; f.w = (float)a.w * FPINV;
            *reinterpret_cast<float4*>(pp + vi) = f;
        } else {
            for (int u = 0; u < 4; ++u)
                if (vi + u < n_vert) pp[vi + u] = (float)acc[v4 + u] * FPINV;
        }
    }
}

// Sum split partials + vertex update; 4 vertices/thread, float4 I/O.
__global__ void final_update_kernel(const float* __restrict__ partials,
                                    const float* __restrict__ va,
                                    const float* __restrict__ g,
                                    float* __restrict__ out, int n_vert,
                                    int split) {
    const int gt = blockIdx.x * blockDim.x + threadIdx.x;
    const float w = g[0];
    const int v0 = gt * 4;
    if (v0 + 4 <= n_vert) {
        float4 c = reinterpret_cast<const float4*>(partials)[gt];
        for (int sp = 1; sp < split; ++sp) {
            float4 c2 = reinterpret_cast<const float4*>(
                            partials + (size_t)sp * n_vert)[gt];
            c.x += c2.x; c.y += c2.y; c.z += c2.z; c.w += c2.w;
        }
        float4 f0 = reinterpret_cast<const float4*>(va)[gt * 3 + 0];
        float4 f1 = reinterpret_cast<const float4*>(va)[gt * 3 + 1];
        float4 f2 = reinterpret_cast<const float4*>(va)[gt * 3 + 2];
        float4 o0, o1, o2;
        o0.x = f0.x; o0.y = f0.y; o0.z = f0.z + w * (f0.y - c.x) / f0.x;
        o0.w = f0.w; o1.x = f1.x; o1.y = f1.y + w * (f1.x - c.y) / f0.w;
        o1.z = f1.z; o1.w = f1.w; o2.x = f2.x + w * (f1.w - c.z) / f1.z;
        o2.y = f2.y; o2.z = f2.z; o2.w = f2.w + w * (f2.z - c.w) / f2.y;
        reinterpret_cast<float4*>(out)[gt * 3 + 0] = o0;
        reinterpret_cast<float4*>(out)[gt * 3 + 1] = o1;
        reinterpret_cast<float4*>(out)[gt * 3 + 2] = o2;
    } else {
        for (int i = v0; i < n_vert; ++i) {
            float c = 0.f;
            for (int sp = 0; sp < split; ++sp)
                c += partials[(size_t)sp * n_vert + i];
            float A = va[3 * i], bb = va[3 * i + 1], x = va[3 * i + 2];
            out[3 * i]     = A;
            out[3 * i + 1] = bb;
            out[3 * i + 2] = x + w * (bb - c) / A;
        }
    }
}

// Fused path (used if partials don't fit in ws) — int fixed-point accumulate.
__global__ void accum_update_kernel(const unsigned long long* __restrict__ pairs,
                                    const int* __restrict__ base,
                                    const float* __restrict__ va,
                                    const float* __restrict__ g,
                                    float* __restrict__ out, int n_vert) {
    __shared__ __align__(16) int acc[VBUCK];
    const int b = blockIdx.x;
    const int T = blockDim.x;                  // 1024
    for (int t = threadIdx.x; t < VBUCK; t += T) acc[t] = 0;
    __syncthreads();
    const int s = base[b];
    const int e = base[b + 1];
    for (int i = s + threadIdx.x; i < e; i += T) {
        unsigned long long p = pairs[i];
        atomicAdd(&acc[(int)(p & (VBUCK - 1))],
                  __float2int_rn(__uint_as_float((unsigned)(p >> 32)) * FPSCALE));
    }
    __syncthreads();

    const float w = g[0];
    const int vbase = b << VSHIFT;
    const int t = threadIdx.x;
    for (int v4 = t * 4; v4 < VBUCK; v4 += T * 4) {
        int vi = vbase + v4;
        if (vi + 4 <= n_vert) {
            const int gt = vi >> 2;
            float4 f0 = reinterpret_cast<const float4*>(va)[gt * 3 + 0];
            float4 f1 = reinterpret_cast<const float4*>(va)[gt * 3 + 1];
            float4 f2 = reinterpret_cast<const float4*>(va)[gt * 3 + 2];
            int4   a  = *reinterpret_cast<const int4*>(&acc[v4]);
            float4 c;
            c.x = (float)a.x * FPINV; c.y = (float)a.y * FPINV;
            c.z = (float)a.z * FPINV; c.w = (float)a.w * FPINV;
            float4 o0, o1, o2;
            o0.x = f0.x; o0.y = f0.y; o0.z = f0.z + w * (f0.y - c.x) / f0.x;
            o0.w = f0.w; o1.x = f1.x; o1.y = f1.y + w * (f1.x - c.y) / f0.w;
            o1.z = f1.z; o1.w = f1.w; o2.x = f2.x + w * (f1.w - c.z) / f1.z;
            o2.y = f2.y; o2.z = f2.z; o2.w = f2.w + w * (f2.z - c.w) / f2.y;
            reinterpret_cast<float4*>(out)[gt * 3 + 0] = o0;
            reinterpret_cast<float4*>(out)[gt * 3 + 1] = o1;
            reinterpret_cast<float4*>(out)[gt * 3 + 2] = o2;
        } else {
            for (int u = 0; u < 4; ++u) {
                int i = vi + u;
                if (i < n_vert) {
                    float A = va[3 * i], bb = va[3 * i + 1], x = va[3 * i + 2];
                    out[3 * i]     = A;
                    out[3 * i + 1] = bb;
                    out[3 * i + 2] = x + w * (bb - (float)acc[v4 + u] * FPINV) / A;
                }
            }
        }
    }
}

// ---- fallback path (insufficient scratch): device-scope atomics ----
__global__ void scatter_add_dev_kernel(const int* __restrict__ dst,
                                       const float* __restrict__ ea,
                                       float* __restrict__ acc, int n_edges4) {
    int i = blockIdx.x * blockDim.x + threadIdx.x;
    const int stride = gridDim.x * blockDim.x;
    for (; i < n_edges4; i += stride) {
        int4   d = reinterpret_cast<const int4*>(dst)[i];
        float4 v = reinterpret_cast<const float4*>(ea)[i];
        atomicAdd(&acc[d.x], v.x);
        atomicAdd(&acc[d.y], v.y);
        atomicAdd(&acc[d.z], v.z);
        atomicAdd(&acc[d.w], v.w);
    }
}

__global__ void update_kernel(const float* __restrict__ va,
                              const float* __restrict__ cbar,
                              const float* __restrict__ g,
                              float* __restrict__ out, int n) {
    int i = blockIdx.x * blockDim.x + threadIdx.x;
    if (i >= n) return;
    float A = va[3 * i], b = va[3 * i + 1], x = va[3 * i + 2];
    out[3 * i]     = A;
    out[3 * i + 1] = b;
    out[3 * i + 2] = x + g[0] * (b - cbar[i]) / A;
}

extern "C" void kernel_launch(void* const* d_in, const int* in_sizes, int n_in,
                              void* d_out, int out_size, void* d_ws, size_t ws_size,
                              hipStream_t stream) {
    const float* vertex_attr = (const float*)d_in[0];
    const int*   edgeij      = (const int*)d_in[1];   // row 0 = dst
    const float* edge_attr   = (const float*)d_in[2];
    const float* g           = (const float*)d_in[3];

    const int       n_vert = in_sizes[0] / 3;
    const long long n_edge = in_sizes[2];
    const int       nb     = (n_vert + VBUCK - 1) >> VSHIFT;   // 62
    const int       nblk   = (int)((n_edge + PBLK - 1) / PBLK);

    // ws layout: [histp_t][histp_b][totals][base][pairs][partials (optional)]
    size_t histt_sz   = (size_t)nblk * RPB * NBMAX * sizeof(int);
    size_t histb_off  = (histt_sz + 255) & ~(size_t)255;
    size_t histb_sz   = (size_t)NBMAX * nblk * sizeof(int);
    size_t totals_off = (histb_off + histb_sz + 255) & ~(size_t)255;
    size_t base_off   = totals_off + NBMAX * sizeof(int);
    size_t pairs_off  = (base_off + (TPB + 1) * sizeof(int) + 255) & ~(size_t)255;
    size_t need1      = pairs_off + (size_t)n_edge * sizeof(unsigned long long);
    size_t part_off   = (need1 + 255) & ~(size_t)255;

    if (ws_size >= need1 && nb <= NBMAX) {
        int* histp_t = (int*)d_ws;
        int* histp_b = (int*)((char*)d_ws + histb_off);
        int* totals  = (int*)((char*)d_ws + totals_off);
        int* basep   = (int*)((char*)d_ws + base_off);
        unsigned long long* pairs =
            (unsigned long long*)((char*)d_ws + pairs_off);

        hist_rounds_kernel<<<nblk, TPB, 0, stream>>>(edgeij, n_edge, nblk,
                                                     histp_t, histp_b);
        row_scan_kernel<<<nb, TPB, 0, stream>>>(histp_b, nblk, totals);
        base_scan_kernel<<<1, TPB, 0, stream>>>(totals, nb, basep);
        partition_kernel<<<nblk, TPB, 0, stream>>>(edgeij, edge_attr, n_edge,
                                                   nblk, histp_t, histp_b,
                                                   basep, pairs);

        int split = 0;
        for (int sp = SPLITMAX; sp >= 2; sp >>= 1) {
            if (ws_size >= part_off + (size_t)sp * n_vert * sizeof(float)) {
                split = sp; break;
            }
        }
        if (split) {
            float* partials = (float*)((char*)d_ws + part_off);
            accum_partial_kernel<<<nb * split, ATPB, 0, stream>>>(
                pairs, basep, partials, n_vert, nb, split);
            const int uthreads = (n_vert + 3) / 4;
            final_update_kernel<<<(uthreads + TPB - 1) / TPB, TPB, 0, stream>>>(
                partials, vertex_attr, g, (float*)d_out, n_vert, split);
        } else {
            accum_update_kernel<<<nb, 1024, 0, stream>>>(pairs, basep, vertex_attr,
                                                         g, (float*)d_out, n_vert);
        }
    } else {
        float* cbar = (float*)d_ws;
        hipMemsetAsync(cbar, 0, (size_t)n_vert * sizeof(float), stream);
        scatter_add_dev_kernel<<<4096, TPB, 0, stream>>>(edgeij, edge_attr, cbar,
                                                         (int)(n_edge / 4));
        update_kernel<<<(n_vert + TPB - 1) / TPB, TPB, 0, stream>>>(
            vertex_attr, cbar, g, (float*)d_out, n_vert);
    }
}